// Round 3
// baseline (237.650 us; speedup 1.0000x reference)
//
#include <hip/hip_runtime.h>

#define BATCH 256
#define NROW  512
#define CDIM  256
#define WAVES 8
#define RPW   (NROW / WAVES)   // 64 rows per wave
#define CHK   16               // rows per register-cached chunk
#define NCHK  (RPW / CHK)      // 4 chunks per wave

// ---------------------------------------------------------------------------
// Kernel 1: qk[b,:] = Wk^T (Wq @ P[b,id[b],:] + bq)         (one block per b)
// Score term Q.bk is constant over n -> softmax-invariant -> dropped.
// ---------------------------------------------------------------------------
__global__ __launch_bounds__(256) void qk_kernel(
    const float* __restrict__ P, const int* __restrict__ idx,
    const float* __restrict__ Wq, const float* __restrict__ bq,
    const float* __restrict__ Wk, float* __restrict__ qk) {
  __shared__ float s_psel[CDIM];
  __shared__ float s_q[CDIM];
  const int b = blockIdx.x;
  const int t = threadIdx.x;

  const float* prow = P + ((size_t)b * NROW + (size_t)idx[b]) * CDIM;
  s_psel[t] = prow[t];
  __syncthreads();

  // Q[d] = dot(Wq[d,:], p_sel) + bq[d]   (thread t = d, contiguous row read)
  {
    const float4* wq4 = (const float4*)(Wq + (size_t)t * CDIM);
    const float4* ps4 = (const float4*)s_psel;
    float acc = 0.f;
#pragma unroll 8
    for (int c4 = 0; c4 < CDIM / 4; ++c4) {
      float4 w = wq4[c4], p = ps4[c4];
      acc += w.x * p.x + w.y * p.y + w.z * p.z + w.w * p.w;
    }
    s_q[t] = acc + bq[t];
  }
  __syncthreads();

  // qk[e] = sum_d Q[d] * Wk[d,e]   (thread t = e, coalesced across threads)
  {
    float acc = 0.f;
#pragma unroll 8
    for (int d = 0; d < CDIM; ++d) acc += s_q[d] * Wk[(size_t)d * CDIM + t];
    qk[(size_t)b * CDIM + t] = acc;
  }
}

// ---------------------------------------------------------------------------
// Kernel 2 (fused): one block per batch, 8 waves x 64 rows each.
// Per wave: online softmax over 4 chunks of 16 register-cached rows
// (P read EXACTLY once, no intra-stream barriers), then 8-way merge in LDS
// and out = Wv @ (ctx/l) + bv.
// ---------------------------------------------------------------------------
__global__ __launch_bounds__(512) void attn_fused_kernel(
    const float* __restrict__ P, const float* __restrict__ qk,
    const float* __restrict__ Wv, const float* __restrict__ bv,
    float* __restrict__ out) {
  const int b = blockIdx.x;
  const int t = threadIdx.x;
  const int lane = t & 63;
  const int w = t >> 6;

  __shared__ float s_ctx[WAVES][CDIM];
  __shared__ float s_m[WAVES], s_l[WAVES];
  __shared__ float s_ctxn[CDIM];
  __shared__ float s_part[2][CDIM];

  // lane holds 4 consecutive qk channels; wave covers all 256
  const float4 qk4 = ((const float4*)(qk + (size_t)b * CDIM))[lane];
  const float* Pw = P + ((size_t)b * NROW + (size_t)w * RPW) * CDIM;

  float m = -1e30f, l = 0.f;
  float4 ctx = make_float4(0.f, 0.f, 0.f, 0.f);

  for (int ch = 0; ch < NCHK; ++ch) {
    // ---- load 16 rows into registers (independent loads -> deep MLP) ----
    float4 pv[CHK];
#pragma unroll
    for (int i = 0; i < CHK; ++i)
      pv[i] = ((const float4*)(Pw + (size_t)(ch * CHK + i) * CDIM))[lane];

    // ---- scores: butterfly reduce; every lane ends with the full dot ----
    float sc[CHK];
#pragma unroll
    for (int i = 0; i < CHK; ++i) {
      float part = pv[i].x * qk4.x + pv[i].y * qk4.y +
                   pv[i].z * qk4.z + pv[i].w * qk4.w;
#pragma unroll
      for (int mm = 32; mm >= 1; mm >>= 1) part += __shfl_xor(part, mm, 64);
      sc[i] = part;
    }

    // ---- online softmax update (wave-uniform m,l; per-lane ctx) ----
    float cmax = sc[0];
#pragma unroll
    for (int i = 1; i < CHK; ++i) cmax = fmaxf(cmax, sc[i]);
    const float mnew = fmaxf(m, cmax);
    const float scale = __expf(m - mnew);  // m=-1e30 first iter -> 0
    l *= scale;
    ctx.x *= scale; ctx.y *= scale; ctx.z *= scale; ctx.w *= scale;
#pragma unroll
    for (int i = 0; i < CHK; ++i) {
      const float p = __expf(sc[i] - mnew);
      l += p;
      ctx.x += p * pv[i].x; ctx.y += p * pv[i].y;
      ctx.z += p * pv[i].z; ctx.w += p * pv[i].w;
    }
    m = mnew;
  }

  // ---- 8-way cross-wave merge ----
  ((float4*)s_ctx[w])[lane] = ctx;
  if (lane == 0) { s_m[w] = m; s_l[w] = l; }
  __syncthreads();

  if (t < CDIM) {
    float mg = s_m[0];
#pragma unroll
    for (int i = 1; i < WAVES; ++i) mg = fmaxf(mg, s_m[i]);
    float lg = 0.f, c = 0.f;
#pragma unroll
    for (int i = 0; i < WAVES; ++i) {
      const float co = __expf(s_m[i] - mg);
      lg += co * s_l[i];
      c  += co * s_ctx[i][t];
    }
    s_ctxn[t] = c / lg;
  }
  __syncthreads();

  // ---- out[d] = dot(Wv[d,:], ctxn) + bv[d]; 2 threads split each dot ----
  {
    const int d = t & (CDIM - 1);
    const int h = t >> 8;  // half selector
    const float4* wv4 =
        (const float4*)(Wv + (size_t)d * CDIM + (size_t)h * (CDIM / 2));
    const float4* cx4 = (const float4*)(s_ctxn + h * (CDIM / 2));
    float acc = 0.f;
#pragma unroll 8
    for (int j = 0; j < CDIM / 8; ++j) {  // 32 float4 = 128 floats per half
      float4 wv = wv4[j], cc = cx4[j];
      acc += wv.x * cc.x + wv.y * cc.y + wv.z * cc.z + wv.w * cc.w;
    }
    s_part[h][d] = acc;
  }
  __syncthreads();
  if (t < CDIM)
    out[(size_t)b * CDIM + t] = s_part[0][t] + s_part[1][t] + bv[t];
}

// ---------------------------------------------------------------------------
extern "C" void kernel_launch(void* const* d_in, const int* in_sizes, int n_in,
                              void* d_out, int out_size, void* d_ws,
                              size_t ws_size, hipStream_t stream) {
  const float* P  = (const float*)d_in[0];
  const int*  idx = (const int*)d_in[1];   // jax default x64-off: int32
  const float* Wq = (const float*)d_in[2];
  const float* bq = (const float*)d_in[3];
  const float* Wk = (const float*)d_in[4];
  // d_in[5] = bk: constant score shift per batch -> softmax-invariant -> unused
  const float* Wv = (const float*)d_in[6];
  const float* bv = (const float*)d_in[7];
  float* out = (float*)d_out;

  float* qk = (float*)d_ws;  // BATCH*CDIM = 65536 floats = 256 KiB

  qk_kernel<<<BATCH, 256, 0, stream>>>(P, idx, Wq, bq, Wk, qk);
  attn_fused_kernel<<<BATCH, 512, 0, stream>>>(P, qk, Wv, bv, out);
}

// Round 4
// 234.294 us; speedup vs baseline: 1.0143x; 1.0143x over previous
//
#include <hip/hip_runtime.h>

#define BATCH 256
#define NROW  512
#define CDIM  256
#define WAVES 8
#define RPW   (NROW / WAVES)   // 64 rows per wave
#define CHK   8                // rows per register chunk (ping-pong buffered)
#define NCHK  (RPW / CHK)      // 8 chunks per wave

// ---------------------------------------------------------------------------
// Fully fused: one block per batch (256 blocks x 512 threads = 8 waves).
//  prologue: qk = Wk^T (Wq @ P[b,id[b]] + bq)      (Wq/Wk are L2-resident)
//  stream:   per wave, online softmax over 64 rows in 8 register chunks,
//            double-buffered so loads stay in flight under the shfl chain.
//            P is read EXACTLY once. Q.bk score term is softmax-invariant.
//  epilogue: 8-way wave merge, out = Wv @ (ctx/l) + bv.
// ---------------------------------------------------------------------------
__global__ __launch_bounds__(512) void attn_one_kernel(
    const float* __restrict__ P, const int* __restrict__ idx,
    const float* __restrict__ Wq, const float* __restrict__ bq,
    const float* __restrict__ Wk, const float* __restrict__ Wv,
    const float* __restrict__ bv, float* __restrict__ out) {
  const int b = blockIdx.x;
  const int t = threadIdx.x;
  const int lane = t & 63;
  const int w = t >> 6;

  __shared__ float s_psel[CDIM];
  __shared__ float s_q[CDIM];
  __shared__ float s_qk[CDIM];
  __shared__ float s_ctx[WAVES][CDIM];
  __shared__ float s_m[WAVES], s_l[WAVES];
  __shared__ float s_ctxn[CDIM];
  __shared__ float s_part[2][CDIM];

  const float* Pw = P + ((size_t)b * NROW + (size_t)w * RPW) * CDIM;

  // ---- issue chunk-0 prefetch first: overlaps with the qk prologue ----
  float4 pv0[CHK], pv1[CHK];
#pragma unroll
  for (int i = 0; i < CHK; ++i)
    pv0[i] = ((const float4*)(Pw + (size_t)i * CDIM))[lane];

  // ---- prologue: qk[b,:] (threads 0..255; waves 4-7 wait at barrier) ----
  if (t < CDIM)
    s_psel[t] = P[((size_t)b * NROW + (size_t)idx[b]) * CDIM + t];
  __syncthreads();

  if (t < CDIM) {  // Q[d] = dot(Wq[d,:], p_sel) + bq[d]
    const float4* wq4 = (const float4*)(Wq + (size_t)t * CDIM);
    const float4* ps4 = (const float4*)s_psel;
    float acc = 0.f;
#pragma unroll 8
    for (int c4 = 0; c4 < CDIM / 4; ++c4) {
      float4 wv = wq4[c4], p = ps4[c4];
      acc += wv.x * p.x + wv.y * p.y + wv.z * p.z + wv.w * p.w;
    }
    s_q[t] = acc + bq[t];
  }
  __syncthreads();

  if (t < CDIM) {  // qk[e] = sum_d Q[d] * Wk[d,e]  (coalesced over e)
    float acc = 0.f;
#pragma unroll 8
    for (int d = 0; d < CDIM; ++d) acc += s_q[d] * Wk[(size_t)d * CDIM + t];
    s_qk[t] = acc;
  }
  __syncthreads();

  const float4 qk4 = ((const float4*)s_qk)[lane];

  float m = -1e30f, l = 0.f;
  float4 ctx = make_float4(0.f, 0.f, 0.f, 0.f);

#define PREFETCH(dst, chn)                                                   \
  {                                                                          \
    _Pragma("unroll") for (int i = 0; i < CHK; ++i) dst[i] =                 \
        ((const float4*)(Pw + (size_t)((chn)*CHK + i) * CDIM))[lane];        \
  }

#define CONSUME(cur)                                                         \
  {                                                                          \
    float sc[CHK];                                                           \
    _Pragma("unroll") for (int i = 0; i < CHK; ++i) {                        \
      float part = cur[i].x * qk4.x + cur[i].y * qk4.y +                     \
                   cur[i].z * qk4.z + cur[i].w * qk4.w;                      \
      _Pragma("unroll") for (int mm = 32; mm >= 1; mm >>= 1)                 \
          part += __shfl_xor(part, mm, 64);                                  \
      sc[i] = part;                                                          \
    }                                                                        \
    float cmax = sc[0];                                                      \
    _Pragma("unroll") for (int i = 1; i < CHK; ++i)                          \
        cmax = fmaxf(cmax, sc[i]);                                           \
    const float mnew = fmaxf(m, cmax);                                       \
    const float scale = __expf(m - mnew); /* m=-1e30 first iter -> 0 */      \
    l *= scale;                                                              \
    ctx.x *= scale; ctx.y *= scale; ctx.z *= scale; ctx.w *= scale;          \
    _Pragma("unroll") for (int i = 0; i < CHK; ++i) {                        \
      const float p = __expf(sc[i] - mnew);                                  \
      l += p;                                                                \
      ctx.x += p * cur[i].x; ctx.y += p * cur[i].y;                          \
      ctx.z += p * cur[i].z; ctx.w += p * cur[i].w;                          \
    }                                                                        \
    m = mnew;                                                                \
  }

  // ---- stream: ping-pong, fully unrolled (static indexing only) ----
#pragma unroll
  for (int cc = 0; cc < NCHK; cc += 2) {
    if (cc + 1 < NCHK) PREFETCH(pv1, cc + 1);
    CONSUME(pv0);
    if (cc + 2 < NCHK) PREFETCH(pv0, cc + 2);
    if (cc + 1 < NCHK) CONSUME(pv1);
  }
#undef PREFETCH
#undef CONSUME

  // ---- 8-way cross-wave merge ----
  ((float4*)s_ctx[w])[lane] = ctx;
  if (lane == 0) { s_m[w] = m; s_l[w] = l; }
  __syncthreads();

  if (t < CDIM) {
    float mg = s_m[0];
#pragma unroll
    for (int i = 1; i < WAVES; ++i) mg = fmaxf(mg, s_m[i]);
    float lg = 0.f, c = 0.f;
#pragma unroll
    for (int i = 0; i < WAVES; ++i) {
      const float co = __expf(s_m[i] - mg);
      lg += co * s_l[i];
      c  += co * s_ctx[i][t];
    }
    s_ctxn[t] = c / lg;
  }
  __syncthreads();

  // ---- out[d] = dot(Wv[d,:], ctxn) + bv[d]; 2 threads split each dot ----
  {
    const int d = t & (CDIM - 1);
    const int h = t >> 8;
    const float4* wv4 =
        (const float4*)(Wv + (size_t)d * CDIM + (size_t)h * (CDIM / 2));
    const float4* cx4 = (const float4*)(s_ctxn + h * (CDIM / 2));
    float acc = 0.f;
#pragma unroll 8
    for (int j = 0; j < CDIM / 8; ++j) {
      float4 wv = wv4[j], cc = cx4[j];
      acc += wv.x * cc.x + wv.y * cc.y + wv.z * cc.z + wv.w * cc.w;
    }
    s_part[h][d] = acc;
  }
  __syncthreads();
  if (t < CDIM)
    out[(size_t)b * CDIM + t] = s_part[0][t] + s_part[1][t] + bv[t];
}

// ---------------------------------------------------------------------------
extern "C" void kernel_launch(void* const* d_in, const int* in_sizes, int n_in,
                              void* d_out, int out_size, void* d_ws,
                              size_t ws_size, hipStream_t stream) {
  const float* P  = (const float*)d_in[0];
  const int*  idx = (const int*)d_in[1];   // jax default x64-off: int32
  const float* Wq = (const float*)d_in[2];
  const float* bq = (const float*)d_in[3];
  const float* Wk = (const float*)d_in[4];
  // d_in[5] = bk: constant score shift per batch -> softmax-invariant -> unused
  const float* Wv = (const float*)d_in[6];
  const float* bv = (const float*)d_in[7];
  float* out = (float*)d_out;

  attn_one_kernel<<<BATCH, 512, 0, stream>>>(P, idx, Wq, bq, Wk, Wv, bv, out);
}